// Round 7
// baseline (133065.637 us; speedup 1.0000x reference)
//
#include <hip/hip_runtime.h>
#include <hip/hip_bf16.h>

#define N_NODES 10000
#define N_EDGES 100000
#define DEPTH   6
#define E_CHUNK 12500   // prep-only chunking (h1 staging); 8 chunks
#define NPB     16      // src nodes per fusedF group
#define NGRP    625     // N_NODES / NPB
#define SLOTS   48      // register msg slots per wave (overflow -> fallback)
#define CCH     16      // c's per chunk
#define NCH     64      // chunks (1024 / CCH)
#define CSPLIT  4       // chunk-range splits per group (load balance)
#define CGRP    (NCH / CSPLIT)   // 16 chunks per block

typedef __attribute__((ext_vector_type(8))) short short8;
typedef __attribute__((ext_vector_type(4))) float f32x4;
typedef unsigned short u16;

__device__ __forceinline__ float bf2f(u16 u) {
    union { float f; unsigned int i; } v; v.i = ((unsigned int)u) << 16; return v.f;
}
__device__ __forceinline__ u16 f2bf(float f) {
    union { float f; unsigned int i; } v; v.f = f;
    unsigned int x = v.i;
    unsigned int r = (x + 0x7fffu + ((x >> 16) & 1u)) >> 16;
    return (u16)r;
}

// async global->LDS, 16B per lane (prep GEMM staging)
__device__ __forceinline__ void gload_lds16(const void* g, void* s) {
    __builtin_amdgcn_global_load_lds((const __attribute__((address_space(1))) void*)g,
                                     (__attribute__((address_space(3))) void*)s, 16, 0, 0);
}

// ---------------- one-time weight prep ----------------
__global__ void k2_transpose_kernel(const float* __restrict__ k2w, u16* __restrict__ k2T) {
    int idx = blockIdx.x * 256 + threadIdx.x;  // 1024*1024
    int n = idx >> 10, k = idx & 1023;
    k2T[idx] = f2bf(k2w[k * 1024 + n]);
}
// W3T[(c*64+o)*64 + i] = k3w[c][i*64+o]  (B^T layout for Y-GEMM, K=i)
__global__ void w3t_kernel(const float* __restrict__ k3w, u16* __restrict__ W3T) {
    int idx = blockIdx.x * 256 + threadIdx.x;  // 65536*64 = 4194304
    int col = idx >> 6, i = idx & 63;
    int c = col >> 6, o = col & 63;
    W3T[idx] = f2bf(k3w[(size_t)c * 4096 + i * 64 + o]);
}

// ---------------- degree / sorting ----------------
__global__ void deg_kernel(const int* __restrict__ ei, float* __restrict__ deg) {
    int e = blockIdx.x * 256 + threadIdx.x;
    if (e < N_EDGES) atomicAdd(&deg[ei[N_EDGES + e]], 1.0f);
}
__global__ void srchist_kernel(const int* __restrict__ ei, int* __restrict__ cnt) {
    int e = blockIdx.x * 256 + threadIdx.x;
    if (e < N_EDGES) atomicAdd(&cnt[ei[e]], 1);
}
// exclusive prefix over 10000 bins -> off[0..10000], single block of 1024
__global__ void scan_kernel(const int* __restrict__ cnt, int* __restrict__ off) {
    __shared__ int part[1024];
    int t = threadIdx.x;
    int base = t * 10;
    int loc[10];
    int s = 0;
#pragma unroll
    for (int k = 0; k < 10; ++k) {
        int b = base + k;
        loc[k] = s;
        if (b < N_NODES) s += cnt[b];
    }
    part[t] = s;
    __syncthreads();
    for (int d = 1; d < 1024; d <<= 1) {
        int v = (t >= d) ? part[t - d] : 0;
        __syncthreads();
        part[t] += v;
        __syncthreads();
    }
    int pre = (t == 0) ? 0 : part[t - 1];
#pragma unroll
    for (int k = 0; k < 10; ++k) {
        int b = base + k;
        if (b <= N_NODES) off[b] = pre + loc[k];
    }
}
__global__ void scatter_kernel(const int* __restrict__ ei, const int* __restrict__ off,
                               int* __restrict__ cur, int* __restrict__ srcS,
                               int* __restrict__ dstS, int* __restrict__ esort) {
    int e = blockIdx.x * 256 + threadIdx.x;
    if (e >= N_EDGES) return;
    int s = ei[e];
    int p = off[s] + atomicAdd(&cur[s], 1);
    srcS[p] = s;
    dstS[p] = ei[N_EDGES + e];
    esort[p] = e;
}

// ---------------- layer 1 (per chunk, SORTED edge order) ----------------
__global__ void gemm1_kernel(const float* __restrict__ ea, const float* __restrict__ k1w,
                             const float* __restrict__ k1b, const int* __restrict__ esort,
                             u16* __restrict__ h1, int e0) {
    int idx = blockIdx.x * 256 + threadIdx.x;  // E_CHUNK*1024
    int c = idx & 1023;
    int erow = (idx >> 10) + e0;     // sorted index
    int eo = esort[erow];            // original edge id
    float acc = k1b[c];
#pragma unroll
    for (int i = 0; i < 6; i++) acc += ea[eo * 6 + i] * k1w[i * 1024 + c];
    h1[idx] = f2bf(fmaxf(acc, 0.0f));
}

// ---------------- 128x128-tile bf16 MFMA GEMM, K=1024 (prep only, verified r2) ----
template <int NOUT, bool RELU>
__global__ __launch_bounds__(256) void gemm128_kernel(
    const u16* __restrict__ A, const u16* __restrict__ BT,
    const float* __restrict__ bias, u16* __restrict__ C, int M) {
    constexpr int K = 1024;
    constexpr int KTILES = 32;
    __shared__ __align__(16) u16 ldsA[3][128 * 32];
    __shared__ __align__(16) u16 ldsB[3][128 * 32];

    const int t = threadIdx.x;
    const int lane = t & 63, w = t >> 6;
    const int wm = w >> 1, wn = w & 1;
    const int fm = lane & 15, q = lane >> 4;
    const int m0 = blockIdx.y * 128;
    const int n0 = blockIdx.x * 128;

    f32x4 acc[4][4];
#pragma unroll
    for (int a = 0; a < 4; a++)
#pragma unroll
        for (int b = 0; b < 4; b++) acc[a][b] = (f32x4){0.f, 0.f, 0.f, 0.f};

    const u16* gA[2]; const u16* gB[2];
    int dL[2];
#pragma unroll
    for (int l = 0; l < 2; l++) {
        int L = l * 256 + t;
        int r = L >> 2;
        int kq = (L & 3) ^ ((r >> 1) & 3);
        int ra = m0 + r; if (ra >= M) ra = M - 1;
        gA[l] = A + (size_t)ra * K + kq * 8;
        gB[l] = BT + (size_t)(n0 + r) * K + kq * 8;
        dL[l] = L * 8;
    }
    const int xq = q ^ ((fm >> 1) & 3);
    const int aB = (wm * 64 + fm) * 32 + xq * 8;
    const int bB = (wn * 64 + fm) * 32 + xq * 8;

#pragma unroll
    for (int tt = 0; tt < 2; tt++) {
#pragma unroll
        for (int l = 0; l < 2; l++) { gload_lds16(gA[l], &ldsA[tt][dL[l]]); gA[l] += 32; }
#pragma unroll
        for (int l = 0; l < 2; l++) { gload_lds16(gB[l], &ldsB[tt][dL[l]]); gB[l] += 32; }
    }
    asm volatile("s_waitcnt vmcnt(4)" ::: "memory");
    __builtin_amdgcn_s_barrier();
    asm volatile("" ::: "memory");

    int cur = 0;
    for (int kt = 0; kt < KTILES; ++kt) {
        const u16* la = ldsA[cur];
        const u16* lb = ldsB[cur];

        short8 af[4], bf[4];
#pragma unroll
        for (int mi = 0; mi < 4; mi++)
            af[mi] = *reinterpret_cast<const short8*>(&la[aB + mi * 512]);
#pragma unroll
        for (int ni = 0; ni < 4; ni++)
            bf[ni] = *reinterpret_cast<const short8*>(&lb[bB + ni * 512]);

        if (kt + 2 < KTILES) {
            int nb = cur + 2; if (nb >= 3) nb -= 3;
#pragma unroll
            for (int l = 0; l < 2; l++) { gload_lds16(gA[l], &ldsA[nb][dL[l]]); gA[l] += 32; }
#pragma unroll
            for (int l = 0; l < 2; l++) { gload_lds16(gB[l], &ldsB[nb][dL[l]]); gB[l] += 32; }
        }

        __builtin_amdgcn_s_setprio(1);
#pragma unroll
        for (int mi = 0; mi < 4; mi++)
#pragma unroll
            for (int ni = 0; ni < 4; ni++)
                acc[mi][ni] = __builtin_amdgcn_mfma_f32_16x16x32_bf16(af[mi], bf[ni], acc[mi][ni], 0, 0, 0);
        __builtin_amdgcn_s_setprio(0);

        if (kt + 2 < KTILES) {
            asm volatile("s_waitcnt vmcnt(4)" ::: "memory");
        } else if (kt + 1 < KTILES) {
            asm volatile("s_waitcnt vmcnt(0)" ::: "memory");
        }
        if (kt + 1 < KTILES) {
            __builtin_amdgcn_s_barrier();
            asm volatile("" ::: "memory");
        }
        cur = cur + 1; if (cur == 3) cur = 0;
    }

#pragma unroll
    for (int mi = 0; mi < 4; mi++) {
#pragma unroll
        for (int ni = 0; ni < 4; ni++) {
            int col = n0 + wn * 64 + ni * 16 + fm;
            float bsv = bias[col];
#pragma unroll
            for (int r = 0; r < 4; r++) {
                int row = m0 + wm * 64 + mi * 16 + q * 4 + r;
                if (row < M) {
                    float v = acc[mi][ni][r] + bsv;
                    if (RELU) v = fmaxf(v, 0.0f);
                    C[(size_t)row * NOUT + col] = f2bf(v);
                }
            }
        }
    }
}

// ---------------- z producers: z + zh/zl split + bterm (block = 4 nodes) ----------
// bterm[n][o] = sum_i z[n][i] * b3[i*64+o]
__global__ __launch_bounds__(256) void z0_kernel(const float* __restrict__ x,
                                                 const float* __restrict__ w,
                                                 const float* __restrict__ b,
                                                 const float* __restrict__ b3,
                                                 float* __restrict__ z,
                                                 u16* __restrict__ zh, u16* __restrict__ zl,
                                                 float* __restrict__ bterm) {
    __shared__ float zrow[4][64];
    int ln = threadIdx.x >> 6;
    int n = blockIdx.x * 4 + ln;
    int o = threadIdx.x & 63;
    float v = x[n] * w[o] + b[o];
    z[(size_t)n * 64 + o] = v;
    u16 hv = f2bf(v);
    zh[(size_t)n * 64 + o] = hv;
    zl[(size_t)n * 64 + o] = f2bf(v - bf2f(hv));
    zrow[ln][o] = v;
    __syncthreads();
    float bt = 0.f;
#pragma unroll 8
    for (int i = 0; i < 64; i++) bt += zrow[ln][i] * b3[i * 64 + o];
    bterm[(size_t)n * 64 + o] = bt;
}

__global__ __launch_bounds__(256) void update_kernel(const float* __restrict__ zin,
                                                     const float* __restrict__ agg,
                                                     const float* __restrict__ deg,
                                                     const float* __restrict__ rootw,
                                                     const float* __restrict__ convb,
                                                     const float* __restrict__ b3,
                                                     float* __restrict__ zout,
                                                     u16* __restrict__ zh, u16* __restrict__ zl,
                                                     float* __restrict__ bterm) {
    __shared__ float zrow[4][64];
    int ln = threadIdx.x >> 6;
    int n = blockIdx.x * 4 + ln;
    int o = threadIdx.x & 63;
    float r = convb[o];
    const float* zr = zin + (size_t)n * 64;
#pragma unroll 8
    for (int i = 0; i < 64; i++) r += zr[i] * rootw[i * 64 + o];
    float d = deg[n];
    d = d < 1.0f ? 1.0f : d;
    float v = agg[(size_t)n * 64 + o] / d + r;
    v = fmaxf(v, 0.0f);
    zout[(size_t)n * 64 + o] = v;
    u16 hv = f2bf(v);
    zh[(size_t)n * 64 + o] = hv;
    zl[(size_t)n * 64 + o] = f2bf(v - bf2f(hv));
    zrow[ln][o] = v;
    __syncthreads();
    float bt = 0.f;
#pragma unroll 8
    for (int i = 0; i < 64; i++) bt += zrow[ln][i] * b3[i * 64 + o];
    bterm[(size_t)n * 64 + o] = bt;
}

// ---------------- fusedF v2: per-node Y (MFMA, fp32 LDS) + branch-free apply ----
// R4 math verbatim (passed verification, absmax 0.0625); implementation fixed:
//  - CSPLIT=4: each block handles CGRP=16 of the 64 c-chunks -> 2500 blocks
//    (~5 occupancy rounds, degree-variance stragglers diluted 4x). Y-work not
//    duplicated; msg merged by the atomic scatter (one pass per split).
//    Block order cs-major: resident W3T slice per XCD = 2 MB (L2-fit).
//  - Branch-free apply: slots predicated by index CLAMP (not if-guards), so
//    all h2 loads are unconditional and hoistable; only the final atomicAdd
//    is guarded. s made scalar via readfirstlane (wave-uniform).
//  - Packed per-slot state (s<<20)|j to hold VGPR pressure.
#define ACC2(u, y0, y1) { m = fmaf(__uint_as_float((u) << 16), (y0), m); \
                          m = fmaf(__uint_as_float((u) & 0xffff0000u), (y1), m); }
__global__ __launch_bounds__(256) void fusedF_kernel(
    const u16* __restrict__ h2s, const u16* __restrict__ W3T,
    const u16* __restrict__ zh, const u16* __restrict__ zl,
    const float* __restrict__ bterm, const int* __restrict__ srcS,
    const int* __restrict__ dstS, const int* __restrict__ binoff,
    float* __restrict__ agg) {
    __shared__ float Ylds[NPB][CCH][64];   // 64 KiB

    const int t = threadIdx.x;
    const int lane = t & 63, w = t >> 6;
    const int fm = lane & 15, q = lane >> 4;
    const int cs  = blockIdx.x / NGRP;        // cs-major ordering
    const int grp = blockIdx.x - cs * NGRP;
    const int n0 = grp * NPB;
    const int c0 = cs * CGRP;

    // A-frags (z rows for this group's 16 nodes), hoisted for all chunks
    const short8 azh0 = *reinterpret_cast<const short8*>(&zh[(size_t)(n0 + fm) * 64 + q * 8]);
    const short8 azh1 = *reinterpret_cast<const short8*>(&zh[(size_t)(n0 + fm) * 64 + 32 + q * 8]);
    const short8 azl0 = *reinterpret_cast<const short8*>(&zl[(size_t)(n0 + fm) * 64 + q * 8]);
    const short8 azl1 = *reinterpret_cast<const short8*>(&zl[(size_t)(n0 + fm) * 64 + 32 + q * 8]);

    // edge slice for this wave
    const int j0 = binoff[n0], j1 = binoff[n0 + NPB];
    const int cnt = j1 - j0;
    const int per = cnt >> 2, rem = cnt & 3;
    const int myc = per + (w < rem ? 1 : 0);
    const int mys = j0 + w * per + (w < rem ? w : rem);
    const int mye = mys + myc;
    const int jcl = (cnt > 0) ? (j1 - 1) : 0;   // clamp target (valid edge)

    // per-slot state: packed (s<<20)|j ; msg accumulators
    float msg[SLOTS];
    int pk[SLOTS];
#pragma unroll
    for (int sl = 0; sl < SLOTS; ++sl) {
        int j = mys + sl; if (j > jcl) j = jcl;
        int sg = srcS[j];
        int s = sg - n0; s = s < 0 ? 0 : (s > 15 ? 15 : s);
        pk[sl] = (s << 20) | j;
        msg[sl] = (cs == 0) ? bterm[(size_t)sg * 64 + lane] : 0.0f;  // garbage for inactive, unused
    }

    for (int cc = 0; cc < CGRP; ++cc) {
        const int ch = c0 + cc;
        __syncthreads();   // prior apply done before Ylds overwrite
        // ---- Y phase: wave w -> subtiles sc = w*16 .. w*16+15
#pragma unroll
        for (int s2 = 0; s2 < 16; ++s2) {
            int sc = w * 16 + s2;
            size_t cb = ((size_t)ch * 1024 + sc * 16 + fm) * 64;
            short8 b0 = *reinterpret_cast<const short8*>(&W3T[cb + q * 8]);
            short8 b1 = *reinterpret_cast<const short8*>(&W3T[cb + 32 + q * 8]);
            f32x4 a = (f32x4){0.f, 0.f, 0.f, 0.f};
            a = __builtin_amdgcn_mfma_f32_16x16x32_bf16(azh0, b0, a, 0, 0, 0);
            a = __builtin_amdgcn_mfma_f32_16x16x32_bf16(azl0, b0, a, 0, 0, 0);
            a = __builtin_amdgcn_mfma_f32_16x16x32_bf16(azh1, b1, a, 0, 0, 0);
            a = __builtin_amdgcn_mfma_f32_16x16x32_bf16(azl1, b1, a, 0, 0, 0);
            int cl = sc >> 2, ob = (sc & 3) * 16 + fm;
#pragma unroll
            for (int r = 0; r < 4; ++r) Ylds[q * 4 + r][cl][ob] = a[r];
        }
        __syncthreads();
        // ---- branch-free apply
        const u16* h2b = h2s + (ch << 4);
        float yreg[16];
        int sprev = -1;
#pragma unroll
        for (int sl = 0; sl < SLOTS; ++sl) {
            int s = __builtin_amdgcn_readfirstlane(pk[sl] >> 20);
            int j = pk[sl] & 0xFFFFF;
            if (s != sprev) {
#pragma unroll
                for (int k2 = 0; k2 < 16; ++k2) yreg[k2] = Ylds[s][k2][lane];
                sprev = s;
            }
            const uint4* hp = reinterpret_cast<const uint4*>(h2b + ((size_t)j << 10));
            uint4 ha = hp[0], hb = hp[1];
            float m = msg[sl];
            ACC2(ha.x, yreg[0], yreg[1]);   ACC2(ha.y, yreg[2], yreg[3]);
            ACC2(ha.z, yreg[4], yreg[5]);   ACC2(ha.w, yreg[6], yreg[7]);
            ACC2(hb.x, yreg[8], yreg[9]);   ACC2(hb.y, yreg[10], yreg[11]);
            ACC2(hb.z, yreg[12], yreg[13]); ACC2(hb.w, yreg[14], yreg[15]);
            msg[sl] = m;
        }
        // ---- overflow fallback (rare): per-chunk direct atomic accumulate
        for (int j = mys + SLOTS; j < mye; ++j) {
            int sg = srcS[j];
            int s = sg - n0;
            float m = (ch == 0) ? bterm[(size_t)sg * 64 + lane] : 0.f;
            const uint4* hp = reinterpret_cast<const uint4*>(h2b + ((size_t)j << 10));
            uint4 ha = hp[0], hb = hp[1];
            ACC2(ha.x, Ylds[s][0][lane], Ylds[s][1][lane]);
            ACC2(ha.y, Ylds[s][2][lane], Ylds[s][3][lane]);
            ACC2(ha.z, Ylds[s][4][lane], Ylds[s][5][lane]);
            ACC2(ha.w, Ylds[s][6][lane], Ylds[s][7][lane]);
            ACC2(hb.x, Ylds[s][8][lane], Ylds[s][9][lane]);
            ACC2(hb.y, Ylds[s][10][lane], Ylds[s][11][lane]);
            ACC2(hb.z, Ylds[s][12][lane], Ylds[s][13][lane]);
            ACC2(hb.w, Ylds[s][14][lane], Ylds[s][15][lane]);
            atomicAdd(&agg[(size_t)dstS[j] * 64 + lane], m);
        }
    }

    // ---- final scatter: one atomic pass per split
#pragma unroll
    for (int sl = 0; sl < SLOTS; ++sl) {
        if (sl < myc) atomicAdd(&agg[(size_t)dstS[mys + sl] * 64 + lane], msg[sl]);
    }
}
#undef ACC2

// ---------------- out = z @ fc2_w + fc2_b ----------------
__global__ void final_kernel(const float* __restrict__ z, const float* __restrict__ w,
                             const float* __restrict__ b, float* __restrict__ out) {
    int n = blockIdx.x * 256 + threadIdx.x;
    if (n >= N_NODES) return;
    float acc = b[0];
#pragma unroll 8
    for (int o = 0; o < 64; o++) acc += z[(size_t)n * 64 + o] * w[o];
    out[n] = acc;
}

// ---------------- diagnostic ----------------
__global__ void dbg_kernel(float* __restrict__ out, float val, int n) {
    int i = blockIdx.x * 256 + threadIdx.x;
    if (i < n) out[i] = val;
}

extern "C" void kernel_launch(void* const* d_in, const int* in_sizes, int n_in,
                              void* d_out, int out_size, void* d_ws, size_t ws_size,
                              hipStream_t stream) {
    const float* x     = (const float*)d_in[0];
    const int*   ei    = (const int*)  d_in[1];
    const float* ea    = (const float*)d_in[2];
    const float* fc1w  = (const float*)d_in[3];
    const float* fc1b  = (const float*)d_in[4];
    const float* k1w   = (const float*)d_in[5];
    const float* k1b   = (const float*)d_in[6];
    const float* k2w   = (const float*)d_in[7];
    const float* k2b   = (const float*)d_in[8];
    const float* k3w   = (const float*)d_in[9];
    const float* k3b   = (const float*)d_in[10];
    const float* rootw = (const float*)d_in[11];
    const float* convb = (const float*)d_in[12];
    const float* fc2w  = (const float*)d_in[13];
    const float* fc2b  = (const float*)d_in[14];
    float* out = (float*)d_out;

    const size_t NEED = 256000000;
    if (ws_size < NEED) {
        dbg_kernel<<<(N_NODES + 255) / 256, 256, 0, stream>>>(out, (float)(ws_size >> 20), N_NODES);
        return;
    }

    char* p = (char*)d_ws;
    auto alloc = [&](size_t bytes) {
        char* r = p;
        p += (bytes + 255) & ~(size_t)255;
        return r;
    };
    u16*   h2s   = (u16*)  alloc((size_t)N_EDGES * 1024 * 2);  // 204.8 MB (sorted order)
    u16*   W3T   = (u16*)  alloc((size_t)65536 * 64 * 2);      // 8.39 MB
    u16*   k2T   = (u16*)  alloc((size_t)1024 * 1024 * 2);     // 2.1 MB (prep)
    u16*   h1ch  = (u16*)  alloc((size_t)E_CHUNK * 1024 * 2);  // 25.6 MB (prep)
    float* zA    = (float*)alloc((size_t)N_NODES * 64 * 4);
    float* zB    = (float*)alloc((size_t)N_NODES * 64 * 4);
    u16*   zhb   = (u16*)  alloc((size_t)N_NODES * 64 * 2);
    u16*   zlb   = (u16*)  alloc((size_t)N_NODES * 64 * 2);
    float* bterm = (float*)alloc((size_t)N_NODES * 64 * 4);
    float* agg   = (float*)alloc((size_t)N_NODES * 64 * 4);
    float* deg   = (float*)alloc((size_t)N_NODES * 4);
    int*   scnt  = (int*)  alloc((size_t)N_NODES * 4);
    int*   scur  = (int*)  alloc((size_t)N_NODES * 4);
    int*   boff  = (int*)  alloc((size_t)(N_NODES + 1) * 4);
    int*   srcS  = (int*)  alloc((size_t)N_EDGES * 4);
    int*   dstS  = (int*)  alloc((size_t)N_EDGES * 4);
    int*   esort = (int*)  alloc((size_t)N_EDGES * 4);

    hipMemsetAsync(deg, 0, (size_t)N_NODES * 4, stream);
    hipMemsetAsync(scnt, 0, (size_t)N_NODES * 4, stream);
    hipMemsetAsync(scur, 0, (size_t)N_NODES * 4, stream);

    // weight prep + degree + src-sort
    k2_transpose_kernel<<<(1024 * 1024) / 256, 256, 0, stream>>>(k2w, k2T);
    w3t_kernel<<<(65536 * 64) / 256, 256, 0, stream>>>(k3w, W3T);
    deg_kernel<<<(N_EDGES + 255) / 256, 256, 0, stream>>>(ei, deg);
    srchist_kernel<<<(N_EDGES + 255) / 256, 256, 0, stream>>>(ei, scnt);
    scan_kernel<<<1, 1024, 0, stream>>>(scnt, boff);
    scatter_kernel<<<(N_EDGES + 255) / 256, 256, 0, stream>>>(ei, boff, scur, srcS, dstS, esort);

    // h2s = relu(relu(ea@k1+b1)@k2+b2), bf16, sorted edge order
    for (int e0 = 0; e0 < N_EDGES; e0 += E_CHUNK) {
        gemm1_kernel<<<(E_CHUNK * 1024) / 256, 256, 0, stream>>>(ea, k1w, k1b, esort, h1ch, e0);
        dim3 g2(1024 / 128, (E_CHUNK + 127) / 128);
        gemm128_kernel<1024, true><<<g2, 256, 0, stream>>>(
            h1ch, k2T, k2b, h2s + (size_t)e0 * 1024, E_CHUNK);
    }

    z0_kernel<<<N_NODES / 4, 256, 0, stream>>>(x, fc1w, fc1b, k3b, zA, zhb, zlb, bterm);

    float* zin = zA;
    float* zout = zB;
    for (int d = 0; d < DEPTH; d++) {
        hipMemsetAsync(agg, 0, (size_t)N_NODES * 64 * 4, stream);
        fusedF_kernel<<<NGRP * CSPLIT, 256, 0, stream>>>(
            h2s, W3T, zhb, zlb, bterm, srcS, dstS, boff, agg);
        update_kernel<<<N_NODES / 4, 256, 0, stream>>>(
            zin, agg, deg, rootw, convb, k3b, zout, zhb, zlb, bterm);
        float* tmp = zin; zin = zout; zout = tmp;
    }

    final_kernel<<<(N_NODES + 255) / 256, 256, 0, stream>>>(zin, fc2w, fc2b, out);
}

// Round 8
// 7502.555 us; speedup vs baseline: 17.7360x; 17.7360x over previous
//
#include <hip/hip_runtime.h>
#include <hip/hip_bf16.h>

#define N_NODES 10000
#define N_EDGES 100000
#define DEPTH   6
#define E_CHUNK 12500   // prep-only chunking (h1 staging); 8 chunks

typedef __attribute__((ext_vector_type(8))) short short8;
typedef __attribute__((ext_vector_type(4))) float f32x4;
typedef unsigned short u16;

__device__ __forceinline__ float bf2f(u16 u) {
    union { float f; unsigned int i; } v; v.i = ((unsigned int)u) << 16; return v.f;
}
__device__ __forceinline__ u16 f2bf(float f) {
    union { float f; unsigned int i; } v; v.f = f;
    unsigned int x = v.i;
    unsigned int r = (x + 0x7fffu + ((x >> 16) & 1u)) >> 16;
    return (u16)r;
}

// async global->LDS, 16B per lane
__device__ __forceinline__ void gload_lds16(const void* g, void* s) {
    __builtin_amdgcn_global_load_lds((const __attribute__((address_space(1))) void*)g,
                                     (__attribute__((address_space(3))) void*)s, 16, 0, 0);
}

// ---------------- one-time weight prep ----------------
__global__ void k2_transpose_kernel(const float* __restrict__ k2w, u16* __restrict__ k2T) {
    int idx = blockIdx.x * 256 + threadIdx.x;  // 1024*1024
    int n = idx >> 10, k = idx & 1023;
    k2T[idx] = f2bf(k2w[k * 1024 + n]);
}
// GEMM3 column n = o*64+i takes k3w column i*64+o (emits ewT[e][o][i] directly)
__global__ void k3_permT_kernel(const float* __restrict__ k3w, u16* __restrict__ k3pT) {
    int idx = blockIdx.x * 256 + threadIdx.x;  // 4096*1024
    int n = idx >> 10, c = idx & 1023;
    k3pT[idx] = f2bf(k3w[(size_t)c * 4096 + (n & 63) * 64 + (n >> 6)]);
}
__global__ void b3_permute_kernel(const float* __restrict__ b3, float* __restrict__ b3p) {
    int n = blockIdx.x * 256 + threadIdx.x;  // 4096
    if (n >= 4096) return;
    b3p[n] = b3[(n & 63) * 64 + (n >> 6)];
}

// ---------------- degree ----------------
__global__ void deg_kernel(const int* __restrict__ ei, float* __restrict__ deg) {
    int e = blockIdx.x * 256 + threadIdx.x;
    if (e < N_EDGES) atomicAdd(&deg[ei[N_EDGES + e]], 1.0f);
}

// ---------------- layer 1 (per chunk): h1 = relu(ea @ k1 + b1), bf16 ----------------
__global__ void gemm1_kernel(const float* __restrict__ ea, const float* __restrict__ k1w,
                             const float* __restrict__ k1b, u16* __restrict__ h1, int e0) {
    int idx = blockIdx.x * 256 + threadIdx.x;  // E_CHUNK*1024
    int c = idx & 1023;
    int e = (idx >> 10) + e0;
    float acc = k1b[c];
#pragma unroll
    for (int i = 0; i < 6; i++) acc += ea[e * 6 + i] * k1w[i * 1024 + c];
    h1[idx] = f2bf(fmaxf(acc, 0.0f));
}

// ---------------- 128x128-tile bf16 MFMA GEMM, K=1024 ----------------
// Verified round-2 pipeline (7461 us total, absmax 0.0625): 3 LDS buffer sets
// (48 KiB total -> 3 blocks/CU), staging runs 2 K-tiles ahead, counted
// s_waitcnt vmcnt(4) at each K-step boundary (never drains to 0 in the main
// loop), 1 raw s_barrier per K-step.
// T2 swizzle (measured 0 conflicts): within a 64B row (4x 16B slots), stored
// slot s holds global k-slot kq = s ^ ((row>>1)&3); read side applies the
// same XOR. gload_lds dest stays linear; the swizzle is applied to the
// per-lane GLOBAL source address (rule #21).
// Session evidence (R0-R7): schedule variants (2ph/counted/8ph), XCD remap,
// B-direct-from-L2, and the Y-factorization all regressed or tied; this
// structure is the measured optimum. NOT bandwidth-bound (R5: 2.8x bytes ->
// +9% time); multi-resource plateau at ~31% MfmaUtil.
// FUSE_MSG=false: C[row][col] = f2bf(acc + bias) (optional relu).
// FUSE_MSG=true (NOUT==4096, C unused): per 128-col n-tile = 2 complete
// o-rows of ewT[e][o][i]; epilogue reduces msg[e][o] = sum_i (ew+b)*z[src,i]
// via 16-lane shuffle -> atomicAdd agg.
template <int NOUT, bool RELU, bool FUSE_MSG>
__global__ __launch_bounds__(256) void gemm128_kernel(
    const u16* __restrict__ A, const u16* __restrict__ BT,
    const float* __restrict__ bias, u16* __restrict__ C, int M,
    const int* __restrict__ ei, const float* __restrict__ z,
    float* __restrict__ agg) {
    constexpr int K = 1024;
    constexpr int KTILES = 32;  // K / 32
    __shared__ __align__(16) u16 ldsA[3][128 * 32];   // 3 x 8 KiB
    __shared__ __align__(16) u16 ldsB[3][128 * 32];   // 3 x 8 KiB

    const int t = threadIdx.x;
    const int lane = t & 63, w = t >> 6;
    const int wm = w >> 1, wn = w & 1;
    const int fm = lane & 15, q = lane >> 4;
    const int m0 = blockIdx.y * 128;   // rows (edges); y = m-tiles
    const int n0 = blockIdx.x * 128;   // cols; x = n-tiles

    f32x4 acc[4][4];
#pragma unroll
    for (int a = 0; a < 4; a++)
#pragma unroll
        for (int b = 0; b < 4; b++) acc[a][b] = (f32x4){0.f, 0.f, 0.f, 0.f};

    // ---- staging setup: 2 A-loads + 2 B-loads (16B each) per thread per K-tile
    // LDS slot L = l*256 + t ; tile-row r = L>>2 ; slot s = L&3 holds global
    // k-slot kq = s ^ ((r>>1)&3) (involution; read side applies same XOR)
    const u16* gA[2]; const u16* gB[2];
    int dL[2];
#pragma unroll
    for (int l = 0; l < 2; l++) {
        int L = l * 256 + t;
        int r = L >> 2;
        int kq = (L & 3) ^ ((r >> 1) & 3);
        int ra = m0 + r; if (ra >= M) ra = M - 1;  // clamp tail rows
        gA[l] = A + (size_t)ra * K + kq * 8;
        gB[l] = BT + (size_t)(n0 + r) * K + kq * 8;
        dL[l] = L * 8;
    }
    // ---- read offsets (u16 units). row = 16-aligned base + fm
    //      => (row>>1)&3 == (fm>>1)&3
    const int xq = q ^ ((fm >> 1) & 3);
    const int aB = (wm * 64 + fm) * 32 + xq * 8;
    const int bB = (wn * 64 + fm) * 32 + xq * 8;

    // ---- prologue: stage K-tiles 0 and 1
#pragma unroll
    for (int tt = 0; tt < 2; tt++) {
#pragma unroll
        for (int l = 0; l < 2; l++) { gload_lds16(gA[l], &ldsA[tt][dL[l]]); gA[l] += 32; }
#pragma unroll
        for (int l = 0; l < 2; l++) { gload_lds16(gB[l], &ldsB[tt][dL[l]]); gB[l] += 32; }
    }
    asm volatile("s_waitcnt vmcnt(4)" ::: "memory");  // tile 0 landed; tile 1 in flight
    __builtin_amdgcn_s_barrier();
    asm volatile("" ::: "memory");

    int cur = 0;
    for (int kt = 0; kt < KTILES; ++kt) {
        const u16* la = ldsA[cur];
        const u16* lb = ldsB[cur];

        short8 af[4], bf[4];
#pragma unroll
        for (int mi = 0; mi < 4; mi++)
            af[mi] = *reinterpret_cast<const short8*>(&la[aB + mi * 512]);
#pragma unroll
        for (int ni = 0; ni < 4; ni++)
            bf[ni] = *reinterpret_cast<const short8*>(&lb[bB + ni * 512]);

        if (kt + 2 < KTILES) {
            int nb = cur + 2; if (nb >= 3) nb -= 3;
#pragma unroll
            for (int l = 0; l < 2; l++) { gload_lds16(gA[l], &ldsA[nb][dL[l]]); gA[l] += 32; }
#pragma unroll
            for (int l = 0; l < 2; l++) { gload_lds16(gB[l], &ldsB[nb][dL[l]]); gB[l] += 32; }
        }

        __builtin_amdgcn_s_setprio(1);
#pragma unroll
        for (int mi = 0; mi < 4; mi++)
#pragma unroll
            for (int ni = 0; ni < 4; ni++)
                acc[mi][ni] = __builtin_amdgcn_mfma_f32_16x16x32_bf16(af[mi], bf[ni], acc[mi][ni], 0, 0, 0);
        __builtin_amdgcn_s_setprio(0);

        // ---- K-step boundary: counted wait (tile kt+1 landed, kt+2 in flight)
        if (kt + 2 < KTILES) {
            asm volatile("s_waitcnt vmcnt(4)" ::: "memory");
        } else if (kt + 1 < KTILES) {
            asm volatile("s_waitcnt vmcnt(0)" ::: "memory");  // final-tile drain only
        }
        if (kt + 1 < KTILES) {
            __builtin_amdgcn_s_barrier();
            asm volatile("" ::: "memory");
        }
        cur = cur + 1; if (cur == 3) cur = 0;
    }

    if (!FUSE_MSG) {
#pragma unroll
        for (int mi = 0; mi < 4; mi++) {
#pragma unroll
            for (int ni = 0; ni < 4; ni++) {
                int col = n0 + wn * 64 + ni * 16 + fm;
                float bsv = bias[col];
#pragma unroll
                for (int r = 0; r < 4; r++) {
                    int row = m0 + wm * 64 + mi * 16 + q * 4 + r;
                    if (row < M) {
                        float v = acc[mi][ni][r] + bsv;
                        if (RELU) v = fmaxf(v, 0.0f);
                        C[(size_t)row * NOUT + col] = f2bf(v);
                    }
                }
            }
        }
    } else {
        const int o = (n0 >> 6) + wn;  // global o index, [0,64)
        float bsv[4];
        int iidx[4];
#pragma unroll
        for (int ni = 0; ni < 4; ni++) {
            bsv[ni] = bias[n0 + wn * 64 + ni * 16 + fm];
            iidx[ni] = ni * 16 + fm;
        }
#pragma unroll
        for (int mi = 0; mi < 4; mi++) {
#pragma unroll
            for (int r = 0; r < 4; r++) {
                int e = m0 + wm * 64 + mi * 16 + q * 4 + r;  // uniform across fm-group
                float partial = 0.f;
                int dst = 0;
                if (e < M) {
                    int src = ei[e];
                    dst = ei[N_EDGES + e];
                    const float* zs = z + (size_t)src * 64;
#pragma unroll
                    for (int ni = 0; ni < 4; ni++)
                        partial += (acc[mi][ni][r] + bsv[ni]) * zs[iidx[ni]];
                }
                partial += __shfl_xor(partial, 1);
                partial += __shfl_xor(partial, 2);
                partial += __shfl_xor(partial, 4);
                partial += __shfl_xor(partial, 8);
                if (fm == 0 && e < M) atomicAdd(&agg[(size_t)dst * 64 + o], partial);
            }
        }
    }
}

// ---------------- z0 = x @ fc1_w + fc1_b ----------------
__global__ void z0_kernel(const float* __restrict__ x, const float* __restrict__ w,
                          const float* __restrict__ b, float* __restrict__ z) {
    int idx = blockIdx.x * 256 + threadIdx.x;  // N*64
    int n = idx >> 6, o = idx & 63;
    z[idx] = x[n] * w[o] + b[o];
}

// ---------------- z_new = relu(agg/deg + z @ root_w + conv_b) ----------------
__global__ __launch_bounds__(256) void update_kernel(const float* __restrict__ zin,
                                                     const float* __restrict__ agg,
                                                     const float* __restrict__ deg,
                                                     const float* __restrict__ rootw,
                                                     const float* __restrict__ convb,
                                                     float* __restrict__ zout) {
    int n = blockIdx.x * 4 + (threadIdx.x >> 6);
    int o = threadIdx.x & 63;
    float r = convb[o];
    const float* zr = zin + (size_t)n * 64;
#pragma unroll 8
    for (int i = 0; i < 64; i++) r += zr[i] * rootw[i * 64 + o];
    float d = deg[n];
    d = d < 1.0f ? 1.0f : d;
    float v = agg[(size_t)n * 64 + o] / d + r;
    zout[(size_t)n * 64 + o] = fmaxf(v, 0.0f);
}

// ---------------- out = z @ fc2_w + fc2_b ----------------
__global__ void final_kernel(const float* __restrict__ z, const float* __restrict__ w,
                             const float* __restrict__ b, float* __restrict__ out) {
    int n = blockIdx.x * 256 + threadIdx.x;
    if (n >= N_NODES) return;
    float acc = b[0];
#pragma unroll 8
    for (int o = 0; o < 64; o++) acc += z[(size_t)n * 64 + o] * w[o];
    out[n] = acc;
}

// ---------------- diagnostic ----------------
__global__ void dbg_kernel(float* __restrict__ out, float val, int n) {
    int i = blockIdx.x * 256 + threadIdx.x;
    if (i < n) out[i] = val;
}

extern "C" void kernel_launch(void* const* d_in, const int* in_sizes, int n_in,
                              void* d_out, int out_size, void* d_ws, size_t ws_size,
                              hipStream_t stream) {
    const float* x     = (const float*)d_in[0];
    const int*   ei    = (const int*)  d_in[1];
    const float* ea    = (const float*)d_in[2];
    const float* fc1w  = (const float*)d_in[3];
    const float* fc1b  = (const float*)d_in[4];
    const float* k1w   = (const float*)d_in[5];
    const float* k1b   = (const float*)d_in[6];
    const float* k2w   = (const float*)d_in[7];
    const float* k2b   = (const float*)d_in[8];
    const float* k3w   = (const float*)d_in[9];
    const float* k3b   = (const float*)d_in[10];
    const float* rootw = (const float*)d_in[11];
    const float* convb = (const float*)d_in[12];
    const float* fc2w  = (const float*)d_in[13];
    const float* fc2b  = (const float*)d_in[14];
    float* out = (float*)d_out;

    const size_t NEED = 249000000;
    if (ws_size < NEED) {
        dbg_kernel<<<(N_NODES + 255) / 256, 256, 0, stream>>>(out, (float)(ws_size >> 20), N_NODES);
        return;
    }

    char* p = (char*)d_ws;
    auto alloc = [&](size_t bytes) {
        char* r = p;
        p += (bytes + 255) & ~(size_t)255;
        return r;
    };
    u16*   h2   = (u16*)  alloc((size_t)N_EDGES * 1024 * 2);   // 204.8 MB (bf16, L3-resident)
    u16*   h1ch = (u16*)  alloc((size_t)E_CHUNK * 1024 * 2);   // 25.6 MB (prep only)
    u16*   k2T  = (u16*)  alloc((size_t)1024 * 1024 * 2);
    u16*   k3pT = (u16*)  alloc((size_t)4096 * 1024 * 2);
    float* b3p  = (float*)alloc(4096 * 4);
    float* zA   = (float*)alloc((size_t)N_NODES * 64 * 4);
    float* zB   = (float*)alloc((size_t)N_NODES * 64 * 4);
    float* agg  = (float*)alloc((size_t)N_NODES * 64 * 4);
    float* deg  = (float*)alloc((size_t)N_NODES * 4);

    hipMemsetAsync(deg, 0, (size_t)N_NODES * 4, stream);

    k2_transpose_kernel<<<(1024 * 1024) / 256, 256, 0, stream>>>(k2w, k2T);
    k3_permT_kernel<<<(4096 * 1024) / 256, 256, 0, stream>>>(k3w, k3pT);
    b3_permute_kernel<<<16, 256, 0, stream>>>(k3b, b3p);
    deg_kernel<<<(N_EDGES + 255) / 256, 256, 0, stream>>>(ei, deg);

    // h2 = relu(relu(ea@k1+b1)@k2+b2), bf16, once (edge_attr depth-invariant)
    for (int e0 = 0; e0 < N_EDGES; e0 += E_CHUNK) {
        gemm1_kernel<<<(E_CHUNK * 1024) / 256, 256, 0, stream>>>(ea, k1w, k1b, h1ch, e0);
        dim3 g2(1024 / 128, (E_CHUNK + 127) / 128);
        gemm128_kernel<1024, true, false><<<g2, 256, 0, stream>>>(
            h1ch, k2T, k2b, h2 + (size_t)e0 * 1024, E_CHUNK, nullptr, nullptr, nullptr);
    }

    z0_kernel<<<(N_NODES * 64) / 256, 256, 0, stream>>>(x, fc1w, fc1b, zA);

    float* zin = zA;
    float* zout = zB;
    for (int d = 0; d < DEPTH; d++) {
        hipMemsetAsync(agg, 0, (size_t)N_NODES * 64 * 4, stream);
        // fused: ew = h2@k3p (+b3p) and agg[dst] += z[src]@ew, no ew materialization
        dim3 g3(4096 / 128, (N_EDGES + 127) / 128);
        gemm128_kernel<4096, false, true><<<g3, 256, 0, stream>>>(
            h2, k3pT, b3p, nullptr, N_EDGES, ei, zin, agg);
        update_kernel<<<N_NODES / 4, 256, 0, stream>>>(zin, agg, deg, rootw, convb, zout);
        float* tmp = zin; zin = zout; zout = tmp;
    }

    final_kernel<<<(N_NODES + 255) / 256, 256, 0, stream>>>(zin, fc2w, fc2b, out);
}